// Round 1
// baseline (755.013 us; speedup 1.0000x reference)
//
#include <hip/hip_runtime.h>
#include <math.h>

// B=4, T=2048, D=2048, K=8 -> S=9 sources per (b,t).
// Outputs concatenated in d_out: routed_hidden [B*T*D], weights [B*T*S], entropy [B*T].
constexpr int Bdim = 4;
constexpr int Tdim = 2048;
constexpr int Ddim = 2048;
constexpr int Kdim = 8;
constexpr int Sdim = Kdim + 1;      // 9
constexpr float EPSF = 1e-8f;

constexpr int THREADS = 512;        // 8 waves
constexpr int FPT     = Ddim / THREADS;  // 4 floats per thread
constexpr int NWAVE   = THREADS / 64;    // 8

// One workgroup per (b,t). 512 threads x 4 floats = 2048 = D.
// v[9][4] = 36 data VGPRs per thread (vs 72 before) -> ~80 VGPR total ->
// __launch_bounds__(512,6) caps at ~85 VGPR = 6 waves/SIMD = 3 blocks/CU (75% occ).
// Softmax is computed ONCE (thread 0) and broadcast via LDS, instead of
// redundantly in all threads.
__global__ __launch_bounds__(THREADS, 6) void bar_routed_kernel(
    const float* __restrict__ embedding,   // [B*T*D]
    const float* __restrict__ blocks,      // [K*B*T*D]
    const float* __restrict__ query,       // [D]
    const float* __restrict__ key_weight,  // [D]
    float* __restrict__ routed,            // [B*T*D]
    float* __restrict__ weights_out,       // [B*T*S]
    float* __restrict__ entropy_out)       // [B*T]
{
    const int bt  = blockIdx.x;           // 0 .. B*T-1
    const int tid = threadIdx.x;          // 0 .. 511
    const int d0  = tid * FPT;

    // q[d] * key_weight[d] for this thread's 4 dims
    const float4 q4 = *reinterpret_cast<const float4*>(query + d0);
    const float4 w4 = *reinterpret_cast<const float4*>(key_weight + d0);
    const float qw[FPT] = {q4.x * w4.x, q4.y * w4.y, q4.z * w4.z, q4.w * w4.w};

    float v[Sdim][FPT];
    float ss[Sdim];   // sum of squares per source (partial)
    float dt[Sdim];   // dot(src, q*w) per source (partial)

    const size_t rowoff = (size_t)bt * Ddim + d0;

    #pragma unroll
    for (int s = 0; s < Sdim; ++s) {
        const float* src = (s == 0)
            ? embedding + rowoff
            : blocks + rowoff + (size_t)(s - 1) * ((size_t)Bdim * Tdim * Ddim);
        const float4 a = *reinterpret_cast<const float4*>(src);
        v[s][0] = a.x; v[s][1] = a.y; v[s][2] = a.z; v[s][3] = a.w;
        float s2 = 0.0f, dd = 0.0f;
        #pragma unroll
        for (int j = 0; j < FPT; ++j) {
            s2 = fmaf(v[s][j], v[s][j], s2);
            dd = fmaf(v[s][j], qw[j], dd);
        }
        ss[s] = s2;
        dt[s] = dd;
    }

    // Wave-64 butterfly: lane 0 ends with the wave total.
    // (offsets 1..8 lower to cheap DPP ops; 16/32 to permlane.)
    #pragma unroll
    for (int s = 0; s < Sdim; ++s) {
        #pragma unroll
        for (int off = 32; off >= 1; off >>= 1) {
            ss[s] += __shfl_xor(ss[s], off, 64);
            dt[s] += __shfl_xor(dt[s], off, 64);
        }
    }

    // Cross-wave (8 waves) partials via LDS.
    __shared__ float red_ss[NWAVE][Sdim];
    __shared__ float red_dt[NWAVE][Sdim];
    __shared__ float wfin[Sdim];
    const int wave = tid >> 6;
    const int lane = tid & 63;
    if (lane == 0) {
        #pragma unroll
        for (int s = 0; s < Sdim; ++s) {
            red_ss[wave][s] = ss[s];
            red_dt[wave][s] = dt[s];
        }
    }
    __syncthreads();

    // Thread 0 finalizes the 9-way softmax once; broadcasts via LDS.
    if (tid == 0) {
        float w[Sdim];
        float lmax = -1e30f;
        #pragma unroll
        for (int s = 0; s < Sdim; ++s) {
            float tss = 0.0f, tdt = 0.0f;
            #pragma unroll
            for (int wv = 0; wv < NWAVE; ++wv) {
                tss += red_ss[wv][s];
                tdt += red_dt[wv][s];
            }
            // logit = dot / sqrt(mean(src^2)+eps); weight*query folded into dt.
            const float logit = tdt * rsqrtf(tss * (1.0f / (float)Ddim) + EPSF);
            w[s] = logit;
            lmax = fmaxf(lmax, logit);
        }
        float esum = 0.0f;
        #pragma unroll
        for (int s = 0; s < Sdim; ++s) {
            w[s] = expf(w[s] - lmax);
            esum += w[s];
        }
        const float inv = 1.0f / esum;
        float ent = 0.0f;
        #pragma unroll
        for (int s = 0; s < Sdim; ++s) {
            w[s] *= inv;
            const float cw = fmaxf(w[s], 1e-12f);
            ent -= cw * logf(cw);
            wfin[s] = w[s];
            weights_out[(size_t)bt * Sdim + s] = w[s];
        }
        entropy_out[bt] = ent;
    }
    __syncthreads();

    // Broadcast weights (conflict-free same-address LDS reads).
    float wv[Sdim];
    #pragma unroll
    for (int s = 0; s < Sdim; ++s) wv[s] = wfin[s];

    // Weighted combine of raw sources from registers; coalesced float4 store.
    float o[FPT];
    #pragma unroll
    for (int j = 0; j < FPT; ++j) {
        float acc = 0.0f;
        #pragma unroll
        for (int s = 0; s < Sdim; ++s) acc = fmaf(wv[s], v[s][j], acc);
        o[j] = acc;
    }
    *reinterpret_cast<float4*>(routed + rowoff) = make_float4(o[0], o[1], o[2], o[3]);
}

extern "C" void kernel_launch(void* const* d_in, const int* in_sizes, int n_in,
                              void* d_out, int out_size, void* d_ws, size_t ws_size,
                              hipStream_t stream) {
    const float* embedding  = (const float*)d_in[0];
    const float* blocks     = (const float*)d_in[1];
    const float* query      = (const float*)d_in[2];
    const float* key_weight = (const float*)d_in[3];

    float* routed      = (float*)d_out;
    float* weights_out = routed + (size_t)Bdim * Tdim * Ddim;
    float* entropy_out = weights_out + (size_t)Bdim * Tdim * Sdim;

    dim3 grid(Bdim * Tdim);
    dim3 block(THREADS);
    bar_routed_kernel<<<grid, block, 0, stream>>>(
        embedding, blocks, query, key_weight, routed, weights_out, entropy_out);
}